// Round 2
// baseline (282.309 us; speedup 1.0000x reference)
//
#include <hip/hip_runtime.h>

// Problem geometry
constexpr int B = 2, X = 256, Y = 256, Z = 64;
constexpr int CO = X * Y * Z;                       // channel stride (elements)
constexpr long long N_PTS   = (long long)B * X * Y * Z;              // 8388608
constexpr long long M_CELLS = (long long)B * (X-1) * (Y-1) * (Z-1);  // 8193150

constexpr int SEG_LEN    = 16;                      // y-rows owned per wave
constexpr int SEGS_PER_X = Y / SEG_LEN;             // 16
constexpr int TPB = 256;                            // 4 waves/block
constexpr int WPB = TPB / 64;
constexpr int NSEG   = B * X * SEGS_PER_X;          // 8192 segments = 8192 waves
constexpr int BLOCKS = NSEG / WPB;                  // 2048

#define DXc 0.1f
#define DYc 0.1f
#define EPSc 1e-10f

__global__ __launch_bounds__(TPB) void loss_main(const float* __restrict__ outs,
                                                 const float* __restrict__ tgts,
                                                 double* __restrict__ partial) {
    const int lane = threadIdx.x & 63;
    const int wave = threadIdx.x >> 6;
    const int seg  = blockIdx.x * WPB + wave;

    // seg = ((b*SEGS_PER_X + sy)*X + x): consecutive waves in a block share the
    // y-segment and have consecutive x -> wave w's (x+1)-row loads hit the lines
    // wave w+1 loads as its own row (same CU L1).
    const int b  = seg >> 12;          // / (SEGS_PER_X * X)
    const int r  = seg & 4095;
    const int sy = r >> 8;             // / X
    const int x  = r & 255;            // % X
    const int y0 = sy * SEG_LEN;
    const bool hasx1 = (x < X - 1);
    // Last y-segment: no row Y exists; cells only up to y=254.
    const int nI = (sy == SEGS_PER_X - 1) ? SEG_LEN : SEG_LEN + 1;

    const float* ob = outs + ((size_t)b * 3 * CO + (size_t)x * Y * Z + (size_t)y0 * Z + lane);
    const float* tb = tgts + ((size_t)b * 4 * CO + (size_t)x * Y * Z + (size_t)y0 * Z + lane);
    const int DXO = Y * Z;             // +1 in x (elements)

    double s_pt = 0.0;                 // pointwise losses
    double s_dv = 0.0;                 // divergence numerator sums

    // previous-row divergence registers (j=0 corners of the current cell)
    float p_bx0=0, p_by0=0, p_bz0=0, p_zc0=0;      // at x
    float p_bx1=0, p_by1=0, p_bz1=0, p_zc1=0;      // at x+1
    float p_bx0s=0, p_by0s=0, p_bz0s=0, p_zc0s=0;  // z+1 (shuffled)
    float p_bx1s=0, p_by1s=0, p_bz1s=0, p_zc1s=0;

    for (int i = 0; i < nI; ++i) {
        const int yo = i * Z;

        // own-row loads (divergence j=1 / pointwise inputs)
        const float bx0 = ob[0 * CO + yo];
        const float by0 = ob[1 * CO + yo];
        const float bz0 = ob[2 * CO + yo];
        const float zc0 = tb[3 * CO + yo];

        float bx1 = 0, by1 = 0, bz1 = 0, zc1 = 0;
        if (hasx1) {                       // wave-uniform
            bx1 = ob[0 * CO + DXO + yo];
            by1 = ob[1 * CO + DXO + yo];
            bz1 = ob[2 * CO + DXO + yo];
            zc1 = tb[3 * CO + DXO + yo];
        }

        // pointwise losses — only for the 16 owned rows (overlap row belongs to next segment)
        if (i < SEG_LEN) {                 // wave-uniform
            const float bxt = tb[0 * CO + yo];
            const float byt = tb[1 * CO + yo];
            const float bzt = tb[2 * CO + yo];
            const float bxt2 = bxt * bxt, byt2 = byt * byt, bzt2 = bzt * bzt;
            const float t1 = bx0 * bx0 + by0 * by0 - bxt2 - byt2;
            const float e1 = t1 * t1 / (bxt2 + byt2 + EPSc);
            const float dd = bz0 - bzt;
            const float dd2 = dd * dd;
            const float e2 = dd2 * dd2 / (bzt2 + EPSc);
            const float cr = bx0 * byt - by0 * bxt;
            const float e3 = cr * cr / (bxt2 + byt2 + bzt2 + EPSc);
            s_pt += (double)(e1 + e2 + e3);
        }

        if (hasx1) {                       // wave-uniform
            // z+1 corners via lane shuffle (stride-1 dim == lane)
            const float bx0s = __shfl_down(bx0, 1);
            const float by0s = __shfl_down(by0, 1);
            const float bz0s = __shfl_down(bz0, 1);
            const float zc0s = __shfl_down(zc0, 1);
            const float bx1s = __shfl_down(bx1, 1);
            const float by1s = __shfl_down(by1, 1);
            const float bz1s = __shfl_down(bz1, 1);
            const float zc1s = __shfl_down(zc1, 1);

            if (i >= 1) {                  // cell at y = y0 + i - 1
                // corner naming v{i}{j}{k}: i=x-offset, j=y-offset, k=z-offset
                // prev row = j0, current row = j1
                const float bx000 = p_bx0,  bx100 = p_bx1,  bx010 = bx0,  bx110 = bx1;
                const float bx001 = p_bx0s, bx101 = p_bx1s, bx011 = bx0s, bx111 = bx1s;
                const float by000 = p_by0,  by100 = p_by1,  by010 = by0,  by110 = by1;
                const float by001 = p_by0s, by101 = p_by1s, by011 = by0s, by111 = by1s;
                const float bz000 = p_bz0,  bz100 = p_bz1,  bz010 = bz0,  bz110 = bz1;
                const float bz001 = p_bz0s, bz101 = p_bz1s, bz011 = bz0s, bz111 = bz1s;
                const float zc000 = p_zc0,  zc100 = p_zc1,  zc010 = zc0,  zc110 = zc1;
                const float zc001 = p_zc0s, zc101 = p_zc1s, zc011 = zc0s, zc111 = zc1s;

                const float SIXTH = 1.0f / 6.0f;
                const float num =
                      0.25f * (bx100 + bx110 + bx101 + bx111) * DYc * 0.5f * (zc101 - zc100 + zc111 - zc110)
                    - 0.25f * (bx000 + bx010 + bx001 + bx011) * DYc * 0.5f * (zc001 - zc000 + zc011 - zc010)
                    + 0.25f * (by010 + by110 + by011 + by111) * DXc * 0.5f * (zc011 - zc010 + zc111 - zc110)
                    - 0.25f * (by000 + by100 + by001 + by101) * DXc * 0.5f * (zc001 - zc000 + zc101 - zc100)
                    + 0.25f * (bz001 + bz011 + bz101 + bz111) * DXc * DYc
                    - 0.25f * (bz000 + bz010 + bz100 + bz110) * DXc * DYc
                    + (bx001 + bx101 + bx111) * DYc * (zc001 - zc101) * SIXTH
                    + (bx011 + bx111 + bx101) * DYc * (zc011 - zc111) * SIXTH
                    + (by101 + by111 + by011) * DXc * (zc101 - zc111) * SIXTH
                    + (by001 + by011 + by111) * DXc * (zc001 - zc011) * SIXTH
                    - (bx000 + bx100 + bx110) * DYc * (zc000 - zc100) * SIXTH
                    - (bx010 + bx110 + bx100) * DYc * (zc010 - zc110) * SIXTH
                    - (by100 + by110 + by010) * DXc * (zc100 - zc110) * SIXTH
                    - (by000 + by010 + by110) * DXc * (zc000 - zc010) * SIXTH;

                const float bxc = 0.125f * (bx000 + bx100 + bx010 + bx110 + bx001 + bx101 + bx011 + bx111);
                const float byc = 0.125f * (by000 + by100 + by010 + by110 + by001 + by101 + by011 + by111);
                const float bzc = 0.125f * (bz000 + bz100 + bz010 + bz110 + bz001 + bz101 + bz011 + bz111);
                const float den = bxc * bxc + byc * byc + bzc * bzc + EPSc;

                if (lane < Z - 1) {        // z=63 cell invalid (shfl garbage)
                    s_dv += (double)(num * num / den);
                }
            }

            // current row becomes previous row
            p_bx0 = bx0;  p_by0 = by0;  p_bz0 = bz0;  p_zc0 = zc0;
            p_bx1 = bx1;  p_by1 = by1;  p_bz1 = bz1;  p_zc1 = zc1;
            p_bx0s = bx0s; p_by0s = by0s; p_bz0s = bz0s; p_zc0s = zc0s;
            p_bx1s = bx1s; p_by1s = by1s; p_bz1s = bz1s; p_zc1s = zc1s;
        }
    }

    // wave reduction (64 lanes)
    for (int off = 32; off > 0; off >>= 1) {
        s_pt += __shfl_down(s_pt, off);
        s_dv += __shfl_down(s_dv, off);
    }

    __shared__ double lds_pt[WPB];
    __shared__ double lds_dv[WPB];
    if (lane == 0) { lds_pt[wave] = s_pt; lds_dv[wave] = s_dv; }
    __syncthreads();
    if (threadIdx.x == 0) {
        double p = 0.0, d = 0.0;
        #pragma unroll
        for (int w = 0; w < WPB; ++w) { p += lds_pt[w]; d += lds_dv[w]; }
        partial[2 * blockIdx.x]     = p;
        partial[2 * blockIdx.x + 1] = d;
    }
}

__global__ __launch_bounds__(256) void loss_finalize(const double* __restrict__ partial,
                                                     float* __restrict__ out) {
    double s0 = 0.0, s1 = 0.0;
    for (int i = threadIdx.x; i < BLOCKS; i += 256) {
        s0 += partial[2 * i];
        s1 += partial[2 * i + 1];
    }
    const int lane = threadIdx.x & 63;
    const int wave = threadIdx.x >> 6;
    for (int off = 32; off > 0; off >>= 1) {
        s0 += __shfl_down(s0, off);
        s1 += __shfl_down(s1, off);
    }
    __shared__ double l0[4], l1[4];
    if (lane == 0) { l0[wave] = s0; l1[wave] = s1; }
    __syncthreads();
    if (threadIdx.x == 0) {
        double p = 0.0, d = 0.0;
        #pragma unroll
        for (int w = 0; w < 4; ++w) { p += l0[w]; d += l1[w]; }
        const double out0 = 1000.0 * (p / (double)N_PTS);
        const double out1 = 100.0 * (d / (double)M_CELLS) / (0.1 * 0.1) / (0.1 * 0.1);
        out[0] = (float)out0;
        out[1] = (float)out1;
    }
}

extern "C" void kernel_launch(void* const* d_in, const int* in_sizes, int n_in,
                              void* d_out, int out_size, void* d_ws, size_t ws_size,
                              hipStream_t stream) {
    const float* outs = (const float*)d_in[0];   // (2,3,256,256,64) f32
    const float* tgts = (const float*)d_in[1];   // (2,4,256,256,64) f32
    float* out = (float*)d_out;                  // 2 scalars f32
    double* partial = (double*)d_ws;             // BLOCKS*2 doubles = 32 KB

    loss_main<<<BLOCKS, TPB, 0, stream>>>(outs, tgts, partial);
    loss_finalize<<<1, 256, 0, stream>>>(partial, out);
}

// Round 3
// 265.393 us; speedup vs baseline: 1.0637x; 1.0637x over previous
//
#include <hip/hip_runtime.h>

// Problem geometry
constexpr int B = 2, X = 256, Y = 256, Z = 64;
constexpr int CO = X * Y * Z;                       // channel stride (elements)
constexpr int YZ = Y * Z;
constexpr long long N_PTS   = (long long)B * X * Y * Z;              // 8388608
constexpr long long M_CELLS = (long long)B * (X-1) * (Y-1) * (Z-1);  // 8193150

constexpr int ROWS = 4;                 // y-rows per wave (row = lane>>4)
constexpr int SEGS = Y / ROWS;          // 64 y-blocks per x
constexpr int TPB  = 256;
constexpr int WPB  = TPB / 64;          // 4 waves/block
constexpr int NSEG   = B * SEGS * X;    // 32768 waves
constexpr int BLOCKS = NSEG / WPB;      // 8192 blocks

#define DXc 0.1f
#define DYc 0.1f
#define EPSc 1e-10f

// component access into a float4 held in regs (unrolled c => compile-time)
#define F4C(v, c) (((c) == 0) ? (v).x : ((c) == 1) ? (v).y : ((c) == 2) ? (v).z : (v).w)

__global__ __launch_bounds__(TPB) void loss_main(const float* __restrict__ outs,
                                                 const float* __restrict__ tgts,
                                                 double* __restrict__ partial) {
    const int lane = threadIdx.x & 63;
    const int wv   = threadIdx.x >> 6;
    const int seg  = blockIdx.x * WPB + wv;

    // seg = ((b*SEGS + sy)*X + x) : x fastest -> neighbor waves touch x+1 rows
    const int b  = seg >> 14;           // / (SEGS*X) = /16384
    const int r  = seg & 16383;
    const int sy = r >> 8;              // / X
    const int x  = r & 255;             // % X
    const int y0 = sy * ROWS;

    const int row = lane >> 4;          // 0..3
    const int zi  = (lane & 15) << 2;   // 0,4,...,60
    const int y_own = y0 + row;
    const int y_up  = (y_own + 1 < Y) ? (y_own + 1) : (Y - 1);  // clamped (masked later)

    const float* ob = outs + (size_t)b * 3 * CO;
    const float* tb = tgts + (size_t)b * 4 * CO;
    const int off00 = x * YZ + y_own * Z + zi;       // (x,   y)
    const int off01 = x * YZ + y_up  * Z + zi;       // (x,   y+1)
    const int off10 = off00 + YZ;                    // (x+1, y)
    const int off11 = off01 + YZ;                    // (x+1, y+1)

    #define LD4(p, off) (*(const float4*)((p) + (off)))

    double s_pt = 0.0;
    double s_dv = 0.0;

    // ---- own-row loads (pointwise + divergence 0-corners) ----
    const float4 obx = LD4(ob, 0 * CO + off00);
    const float4 oby = LD4(ob, 1 * CO + off00);
    const float4 obz = LD4(ob, 2 * CO + off00);
    const float4 tbx = LD4(tb, 0 * CO + off00);
    const float4 tby = LD4(tb, 1 * CO + off00);
    const float4 tbz = LD4(tb, 2 * CO + off00);
    const float4 tzc = LD4(tb, 3 * CO + off00);

    // ---- pointwise losses (all 4 components valid) ----
    #pragma unroll
    for (int c = 0; c < 4; ++c) {
        const float bxp = F4C(obx, c), byp = F4C(oby, c), bzp = F4C(obz, c);
        const float bxt = F4C(tbx, c), byt = F4C(tby, c), bzt = F4C(tbz, c);
        const float bxt2 = bxt * bxt, byt2 = byt * byt, bzt2 = bzt * bzt;
        const float t1 = bxp * bxp + byp * byp - bxt2 - byt2;
        const float e1 = t1 * t1 / (bxt2 + byt2 + EPSc);
        const float dd = bzp - bzt;
        const float dd2 = dd * dd;
        const float e2 = dd2 * dd2 / (bzt2 + EPSc);
        const float cr = bxp * byt - byp * bxt;
        const float e3 = cr * cr / (bxt2 + byt2 + bzt2 + EPSc);
        s_pt += (double)(e1 + e2 + e3);
    }

    if (x < X - 1) {                    // wave-uniform: divergence cells exist
        // stencil loads: (x+1,y), (x,y+1), (x+1,y+1) for bx,by,bz,zc
        const float4 obx1  = LD4(ob, 0 * CO + off10);
        const float4 oby1  = LD4(ob, 1 * CO + off10);
        const float4 obz1  = LD4(ob, 2 * CO + off10);
        const float4 tzc1  = LD4(tb, 3 * CO + off10);
        const float4 obxy  = LD4(ob, 0 * CO + off01);
        const float4 obyy  = LD4(ob, 1 * CO + off01);
        const float4 obzy  = LD4(ob, 2 * CO + off01);
        const float4 tzcy  = LD4(tb, 3 * CO + off01);
        const float4 obxy1 = LD4(ob, 0 * CO + off11);
        const float4 obyy1 = LD4(ob, 1 * CO + off11);
        const float4 obzy1 = LD4(ob, 2 * CO + off11);
        const float4 tzcy1 = LD4(tb, 3 * CO + off11);

        // z+1 for component 3 comes from lane+1's component 0
        const float n_obx   = __shfl_down(obx.x,   1);
        const float n_oby   = __shfl_down(oby.x,   1);
        const float n_obz   = __shfl_down(obz.x,   1);
        const float n_tzc   = __shfl_down(tzc.x,   1);
        const float n_obx1  = __shfl_down(obx1.x,  1);
        const float n_oby1  = __shfl_down(oby1.x,  1);
        const float n_obz1  = __shfl_down(obz1.x,  1);
        const float n_tzc1  = __shfl_down(tzc1.x,  1);
        const float n_obxy  = __shfl_down(obxy.x,  1);
        const float n_obyy  = __shfl_down(obyy.x,  1);
        const float n_obzy  = __shfl_down(obzy.x,  1);
        const float n_tzcy  = __shfl_down(tzcy.x,  1);
        const float n_obxy1 = __shfl_down(obxy1.x, 1);
        const float n_obyy1 = __shfl_down(obyy1.x, 1);
        const float n_obzy1 = __shfl_down(obzy1.x, 1);
        const float n_tzcy1 = __shfl_down(tzcy1.x, 1);

        const bool yvalid = (y_own < Y - 1);
        const float SIXTH = 1.0f / 6.0f;

        #pragma unroll
        for (int c = 0; c < 4; ++c) {
            // corner v{i}{j}{k}: i=x-offset, j=y-offset, k=z-offset
            const float bx000 = F4C(obx, c),   bx100 = F4C(obx1, c);
            const float bx010 = F4C(obxy, c),  bx110 = F4C(obxy1, c);
            const float by000 = F4C(oby, c),   by100 = F4C(oby1, c);
            const float by010 = F4C(obyy, c),  by110 = F4C(obyy1, c);
            const float bz000 = F4C(obz, c),   bz100 = F4C(obz1, c);
            const float bz010 = F4C(obzy, c),  bz110 = F4C(obzy1, c);
            const float zc000 = F4C(tzc, c),   zc100 = F4C(tzc1, c);
            const float zc010 = F4C(tzcy, c),  zc110 = F4C(tzcy1, c);

            const float bx001 = (c < 3) ? F4C(obx, c + 1)   : n_obx;
            const float bx101 = (c < 3) ? F4C(obx1, c + 1)  : n_obx1;
            const float bx011 = (c < 3) ? F4C(obxy, c + 1)  : n_obxy;
            const float bx111 = (c < 3) ? F4C(obxy1, c + 1) : n_obxy1;
            const float by001 = (c < 3) ? F4C(oby, c + 1)   : n_oby;
            const float by101 = (c < 3) ? F4C(oby1, c + 1)  : n_oby1;
            const float by011 = (c < 3) ? F4C(obyy, c + 1)  : n_obyy;
            const float by111 = (c < 3) ? F4C(obyy1, c + 1) : n_obyy1;
            const float bz001 = (c < 3) ? F4C(obz, c + 1)   : n_obz;
            const float bz101 = (c < 3) ? F4C(obz1, c + 1)  : n_obz1;
            const float bz011 = (c < 3) ? F4C(obzy, c + 1)  : n_obzy;
            const float bz111 = (c < 3) ? F4C(obzy1, c + 1) : n_obzy1;
            const float zc001 = (c < 3) ? F4C(tzc, c + 1)   : n_tzc;
            const float zc101 = (c < 3) ? F4C(tzc1, c + 1)  : n_tzc1;
            const float zc011 = (c < 3) ? F4C(tzcy, c + 1)  : n_tzcy;
            const float zc111 = (c < 3) ? F4C(tzcy1, c + 1) : n_tzcy1;

            const float num =
                  0.25f * (bx100 + bx110 + bx101 + bx111) * DYc * 0.5f * (zc101 - zc100 + zc111 - zc110)
                - 0.25f * (bx000 + bx010 + bx001 + bx011) * DYc * 0.5f * (zc001 - zc000 + zc011 - zc010)
                + 0.25f * (by010 + by110 + by011 + by111) * DXc * 0.5f * (zc011 - zc010 + zc111 - zc110)
                - 0.25f * (by000 + by100 + by001 + by101) * DXc * 0.5f * (zc001 - zc000 + zc101 - zc100)
                + 0.25f * (bz001 + bz011 + bz101 + bz111) * DXc * DYc
                - 0.25f * (bz000 + bz010 + bz100 + bz110) * DXc * DYc
                + (bx001 + bx101 + bx111) * DYc * (zc001 - zc101) * SIXTH
                + (bx011 + bx111 + bx101) * DYc * (zc011 - zc111) * SIXTH
                + (by101 + by111 + by011) * DXc * (zc101 - zc111) * SIXTH
                + (by001 + by011 + by111) * DXc * (zc001 - zc011) * SIXTH
                - (bx000 + bx100 + bx110) * DYc * (zc000 - zc100) * SIXTH
                - (bx010 + bx110 + bx100) * DYc * (zc010 - zc110) * SIXTH
                - (by100 + by110 + by010) * DXc * (zc100 - zc110) * SIXTH
                - (by000 + by010 + by110) * DXc * (zc000 - zc010) * SIXTH;

            const float bxc = 0.125f * (bx000 + bx100 + bx010 + bx110 + bx001 + bx101 + bx011 + bx111);
            const float byc = 0.125f * (by000 + by100 + by010 + by110 + by001 + by101 + by011 + by111);
            const float bzc = 0.125f * (bz000 + bz100 + bz010 + bz110 + bz001 + bz101 + bz011 + bz111);
            const float den = bxc * bxc + byc * byc + bzc * bzc + EPSc;

            const bool zvalid = (zi + c) < (Z - 1);
            if (yvalid && zvalid) {
                s_dv += (double)(num * num / den);
            }
        }
    }

    // wave reduction (64 lanes)
    for (int off = 32; off > 0; off >>= 1) {
        s_pt += __shfl_down(s_pt, off);
        s_dv += __shfl_down(s_dv, off);
    }

    __shared__ double lds_pt[WPB];
    __shared__ double lds_dv[WPB];
    if (lane == 0) { lds_pt[wv] = s_pt; lds_dv[wv] = s_dv; }
    __syncthreads();
    if (threadIdx.x == 0) {
        double p = 0.0, d = 0.0;
        #pragma unroll
        for (int w = 0; w < WPB; ++w) { p += lds_pt[w]; d += lds_dv[w]; }
        partial[2 * blockIdx.x]     = p;
        partial[2 * blockIdx.x + 1] = d;
    }
}

__global__ __launch_bounds__(256) void loss_finalize(const double* __restrict__ partial,
                                                     float* __restrict__ out) {
    double s0 = 0.0, s1 = 0.0;
    for (int i = threadIdx.x; i < BLOCKS; i += 256) {
        s0 += partial[2 * i];
        s1 += partial[2 * i + 1];
    }
    const int lane = threadIdx.x & 63;
    const int wave = threadIdx.x >> 6;
    for (int off = 32; off > 0; off >>= 1) {
        s0 += __shfl_down(s0, off);
        s1 += __shfl_down(s1, off);
    }
    __shared__ double l0[4], l1[4];
    if (lane == 0) { l0[wave] = s0; l1[wave] = s1; }
    __syncthreads();
    if (threadIdx.x == 0) {
        double p = 0.0, d = 0.0;
        #pragma unroll
        for (int w = 0; w < 4; ++w) { p += l0[w]; d += l1[w]; }
        const double out0 = 1000.0 * (p / (double)N_PTS);
        const double out1 = 100.0 * (d / (double)M_CELLS) / (0.1 * 0.1) / (0.1 * 0.1);
        out[0] = (float)out0;
        out[1] = (float)out1;
    }
}

extern "C" void kernel_launch(void* const* d_in, const int* in_sizes, int n_in,
                              void* d_out, int out_size, void* d_ws, size_t ws_size,
                              hipStream_t stream) {
    const float* outs = (const float*)d_in[0];   // (2,3,256,256,64) f32
    const float* tgts = (const float*)d_in[1];   // (2,4,256,256,64) f32
    float* out = (float*)d_out;                  // 2 scalars f32
    double* partial = (double*)d_ws;             // BLOCKS*2 doubles = 128 KB

    loss_main<<<BLOCKS, TPB, 0, stream>>>(outs, tgts, partial);
    loss_finalize<<<1, 256, 0, stream>>>(partial, out);
}

// Round 4
// 264.168 us; speedup vs baseline: 1.0687x; 1.0046x over previous
//
#include <hip/hip_runtime.h>

// Problem geometry
constexpr int B = 2, X = 256, Y = 256, Z = 64;
constexpr int CO = X * Y * Z;                       // channel stride (elements)
constexpr int YZ = Y * Z;
constexpr long long N_PTS   = (long long)B * X * Y * Z;              // 8388608
constexpr long long M_CELLS = (long long)B * (X-1) * (Y-1) * (Z-1);  // 8193150

constexpr int ROWS = 4;                 // y-rows per wave (row = lane>>4)
constexpr int SEGS = Y / ROWS;          // 64 y-blocks per x
constexpr int TPB  = 256;
constexpr int WPB  = TPB / 64;          // 4 waves/block
constexpr int NSEG   = B * SEGS * X;    // 32768 waves
constexpr int BLOCKS = NSEG / WPB;      // 8192 blocks

#define EPSc 1e-10f
#define SIXTH (1.0f / 6.0f)
#define RCPF(v) __builtin_amdgcn_rcpf(v)

// component access into a float4 held in regs (unrolled c => compile-time)
#define F4C(v, c) (((c) == 0) ? (v).x : ((c) == 1) ? (v).y : ((c) == 2) ? (v).z : (v).w)

__global__ __launch_bounds__(TPB, 4) void loss_main(const float* __restrict__ outs,
                                                    const float* __restrict__ tgts,
                                                    double* __restrict__ partial) {
    const int lane = threadIdx.x & 63;
    const int wv   = threadIdx.x >> 6;
    const int seg  = blockIdx.x * WPB + wv;

    // seg = ((b*SEGS + sy)*X + x) : x fastest -> neighbor waves share stencil rows in L1/L2
    const int b  = seg >> 14;           // / (SEGS*X)
    const int r  = seg & 16383;
    const int sy = r >> 8;              // / X
    const int x  = r & 255;             // % X
    const int y0 = sy * ROWS;

    const int row = lane >> 4;          // 0..3
    const int zi  = (lane & 15) << 2;   // 0,4,...,60
    const int y_own = y0 + row;
    const int y_up  = (y_own + 1 < Y) ? (y_own + 1) : (Y - 1);   // clamped, masked later
    const int x_up  = (x + 1 < X) ? (x + 1) : (X - 1);           // clamped, masked later
    const bool xvalid = (x < X - 1);
    const bool yvalid = (y_own < Y - 1);

    const float* ob = outs + (size_t)b * 3 * CO;
    const float* tb = tgts + (size_t)b * 4 * CO;
    const int off00 = x    * YZ + y_own * Z + zi;    // (x,   y)
    const int off01 = x    * YZ + y_up  * Z + zi;    // (x,   y+1)
    const int off10 = x_up * YZ + y_own * Z + zi;    // (x+1, y)
    const int off11 = x_up * YZ + y_up  * Z + zi;    // (x+1, y+1)

    #define LD4(p, off) (*(const float4*)((p) + (off)))

    // ---- all 19 loads issued up front, no dependent compute between ----
    const float4 obx   = LD4(ob, 0 * CO + off00);
    const float4 oby   = LD4(ob, 1 * CO + off00);
    const float4 obz   = LD4(ob, 2 * CO + off00);
    const float4 tbx   = LD4(tb, 0 * CO + off00);
    const float4 tby   = LD4(tb, 1 * CO + off00);
    const float4 tbz   = LD4(tb, 2 * CO + off00);
    const float4 tzc   = LD4(tb, 3 * CO + off00);
    const float4 obx1  = LD4(ob, 0 * CO + off10);
    const float4 oby1  = LD4(ob, 1 * CO + off10);
    const float4 obz1  = LD4(ob, 2 * CO + off10);
    const float4 tzc1  = LD4(tb, 3 * CO + off10);
    const float4 obxy  = LD4(ob, 0 * CO + off01);
    const float4 obyy  = LD4(ob, 1 * CO + off01);
    const float4 obzy  = LD4(ob, 2 * CO + off01);
    const float4 tzcy  = LD4(tb, 3 * CO + off01);
    const float4 obxy1 = LD4(ob, 0 * CO + off11);
    const float4 obyy1 = LD4(ob, 1 * CO + off11);
    const float4 obzy1 = LD4(ob, 2 * CO + off11);
    const float4 tzcy1 = LD4(tb, 3 * CO + off11);

    double s_pt = 0.0;
    double s_dv = 0.0;

    // ---- pointwise losses (f32 inner accumulation over 4 z, then one f64 add) ----
    {
        float pt4 = 0.0f;
        #pragma unroll
        for (int c = 0; c < 4; ++c) {
            const float bxp = F4C(obx, c), byp = F4C(oby, c), bzp = F4C(obz, c);
            const float bxt = F4C(tbx, c), byt = F4C(tby, c), bzt = F4C(tbz, c);
            const float bxt2 = bxt * bxt, byt2 = byt * byt, bzt2 = bzt * bzt;
            const float dxy = bxt2 + byt2;
            const float t1 = bxp * bxp + byp * byp - dxy;
            const float e1 = t1 * t1 * RCPF(dxy + EPSc);
            const float dd = bzp - bzt;
            const float dd2 = dd * dd;
            const float e2 = dd2 * dd2 * RCPF(bzt2 + EPSc);
            const float cr = bxp * byt - byp * bxt;
            const float e3 = cr * cr * RCPF(dxy + bzt2 + EPSc);
            pt4 += e1 + e2 + e3;
        }
        s_pt += (double)pt4;
    }

    // ---- divergence: per-z-level shared partial sums ----
    // num = 0.1*(0.125*fx + G2(k1) - G2(k0));  den = 0.015625*(SxS^2+SyS^2+SzS^2)+EPS
    if (xvalid) {                        // wave-uniform
        float sxp[5], sxm[5], syp[5], sym[5];
        float zxp[5], zxm[5], zyp[5], zym[5];
        float Sx[5], Sy[5], Sz[5], G2[5];

        #pragma unroll
        for (int t = 0; t < 4; ++t) {
            const float bx00 = F4C(obx, t),   bx10 = F4C(obx1, t);
            const float bx01 = F4C(obxy, t),  bx11 = F4C(obxy1, t);
            const float by00 = F4C(oby, t),   by10 = F4C(oby1, t);
            const float by01 = F4C(obyy, t),  by11 = F4C(obyy1, t);
            const float bz00 = F4C(obz, t),   bz10 = F4C(obz1, t);
            const float bz01 = F4C(obzy, t),  bz11 = F4C(obzy1, t);
            const float zc00 = F4C(tzc, t),   zc10 = F4C(tzc1, t);
            const float zc01 = F4C(tzcy, t),  zc11 = F4C(tzcy1, t);

            sxp[t] = bx10 + bx11;   sxm[t] = bx00 + bx01;
            syp[t] = by01 + by11;   sym[t] = by00 + by10;
            zxp[t] = zc10 + zc11;   zxm[t] = zc00 + zc01;
            zyp[t] = zc01 + zc11;   zym[t] = zc00 + zc10;
            Sx[t] = sxp[t] + sxm[t];
            Sy[t] = syp[t] + sym[t];
            Sz[t] = (bz00 + bz01) + (bz10 + bz11);
            G2[t] = 0.025f * Sz[t]
                  + SIXTH * ((bx00 + sxp[t]) * (zc00 - zc10)
                           + (bx01 + sxp[t]) * (zc01 - zc11)
                           + (by10 + syp[t]) * (zc10 - zc11)
                           + (by00 + syp[t]) * (zc00 - zc01));
        }
        // level 4 = lane+1's level 0 (z is the lane-contiguous dim)
        sxp[4] = __shfl_down(sxp[0], 1);
        sxm[4] = __shfl_down(sxm[0], 1);
        syp[4] = __shfl_down(syp[0], 1);
        sym[4] = __shfl_down(sym[0], 1);
        zxp[4] = __shfl_down(zxp[0], 1);
        zxm[4] = __shfl_down(zxm[0], 1);
        zyp[4] = __shfl_down(zyp[0], 1);
        zym[4] = __shfl_down(zym[0], 1);
        Sz[4]  = __shfl_down(Sz[0],  1);
        G2[4]  = __shfl_down(G2[0],  1);
        Sx[4] = sxp[4] + sxm[4];
        Sy[4] = syp[4] + sym[4];

        float dv4 = 0.0f;
        #pragma unroll
        for (int c = 0; c < 4; ++c) {
            const float fx = (sxp[c] + sxp[c+1]) * (zxp[c+1] - zxp[c])
                           - (sxm[c] + sxm[c+1]) * (zxm[c+1] - zxm[c])
                           + (syp[c] + syp[c+1]) * (zyp[c+1] - zyp[c])
                           - (sym[c] + sym[c+1]) * (zym[c+1] - zym[c]);
            const float num2 = 0.125f * fx + (G2[c+1] - G2[c]);
            const float SxS = Sx[c] + Sx[c+1];
            const float SyS = Sy[c] + Sy[c+1];
            const float SzS = Sz[c] + Sz[c+1];
            const float q = SxS * SxS + SyS * SyS + SzS * SzS;
            const float den = 0.015625f * q + EPSc;
            const float v = num2 * num2 * RCPF(den);
            const bool ok = yvalid && ((zi + c) < Z - 1);
            dv4 += ok ? v : 0.0f;
        }
        s_dv += (double)dv4;
    }

    // wave reduction (64 lanes)
    for (int off = 32; off > 0; off >>= 1) {
        s_pt += __shfl_down(s_pt, off);
        s_dv += __shfl_down(s_dv, off);
    }

    __shared__ double lds_pt[WPB];
    __shared__ double lds_dv[WPB];
    if (lane == 0) { lds_pt[wv] = s_pt; lds_dv[wv] = s_dv; }
    __syncthreads();
    if (threadIdx.x == 0) {
        double p = 0.0, d = 0.0;
        #pragma unroll
        for (int w = 0; w < WPB; ++w) { p += lds_pt[w]; d += lds_dv[w]; }
        partial[2 * blockIdx.x]     = p;
        partial[2 * blockIdx.x + 1] = d;
    }
}

__global__ __launch_bounds__(256) void loss_finalize(const double* __restrict__ partial,
                                                     float* __restrict__ out) {
    double s0 = 0.0, s1 = 0.0;
    for (int i = threadIdx.x; i < BLOCKS; i += 256) {
        s0 += partial[2 * i];
        s1 += partial[2 * i + 1];
    }
    const int lane = threadIdx.x & 63;
    const int wave = threadIdx.x >> 6;
    for (int off = 32; off > 0; off >>= 1) {
        s0 += __shfl_down(s0, off);
        s1 += __shfl_down(s1, off);
    }
    __shared__ double l0[4], l1[4];
    if (lane == 0) { l0[wave] = s0; l1[wave] = s1; }
    __syncthreads();
    if (threadIdx.x == 0) {
        double p = 0.0, d = 0.0;
        #pragma unroll
        for (int w = 0; w < 4; ++w) { p += l0[w]; d += l1[w]; }
        // out0 = W_B*loss_b + W_PARALLEL*loss_parallel = 1000 * sum_pt / N
        const double out0 = 1000.0 * (p / (double)N_PTS);
        // s_dv accumulates v = num2^2/den with num = 0.1*num2:
        //   num^2/den = 0.01 * v
        //   out1 = 100 * (0.01 * sum_v / M) / (DX^2*DY^2 = 1e-4) = 1e4 * sum_v / M
        const double out1 = 10000.0 * (d / (double)M_CELLS);
        out[0] = (float)out0;
        out[1] = (float)out1;
    }
}

extern "C" void kernel_launch(void* const* d_in, const int* in_sizes, int n_in,
                              void* d_out, int out_size, void* d_ws, size_t ws_size,
                              hipStream_t stream) {
    const float* outs = (const float*)d_in[0];   // (2,3,256,256,64) f32
    const float* tgts = (const float*)d_in[1];   // (2,4,256,256,64) f32
    float* out = (float*)d_out;                  // 2 scalars f32
    double* partial = (double*)d_ws;             // BLOCKS*2 doubles = 128 KB

    loss_main<<<BLOCKS, TPB, 0, stream>>>(outs, tgts, partial);
    loss_finalize<<<1, 256, 0, stream>>>(partial, out);
}

// Round 6
// 253.892 us; speedup vs baseline: 1.1119x; 1.0405x over previous
//
#include <hip/hip_runtime.h>
#include <stdint.h>

// Problem geometry
constexpr int B = 2, X = 256, Y = 256, Z = 64;
constexpr int CO = X * Y * Z;                       // channel stride (elements)
constexpr int YZ = Y * Z;
constexpr long long N_PTS   = (long long)B * X * Y * Z;              // 8388608
constexpr long long M_CELLS = (long long)B * (X-1) * (Y-1) * (Z-1);  // 8193150

constexpr int RPB = 16;                 // y-rows per block
constexpr int TPB = 256;                // 4 waves
constexpr int WPB = TPB / 64;
constexpr int BLOCKS = B * (Y / RPB) * X;   // 8192

// LDS: 8 streams = (col in {x,x+1}) x (ch in {bx,by,bz,zc}); each 17 rows x 64 z
constexpr int SSTRIDE = 1152;           // floats per stream: 17*64=1088 + 64 slack

#define EPSc 1e-10f
#define SIXTH (1.0f / 6.0f)
#define RCPF(v) __builtin_amdgcn_rcpf(v)

// native 4-float vector (works with __builtin_nontemporal_load, has .x/.y/.z/.w)
typedef float fvec4 __attribute__((ext_vector_type(4)));

#define F4C(v, c) (((c) == 0) ? (v).x : ((c) == 1) ? (v).y : ((c) == 2) ? (v).z : (v).w)

typedef const __attribute__((address_space(1))) uint32_t* gptr_t;
typedef __attribute__((address_space(3))) uint32_t* lptr_t;

__global__ __launch_bounds__(TPB, 4) void loss_main(const float* __restrict__ outs,
                                                    const float* __restrict__ tgts,
                                                    double* __restrict__ partial) {
    __shared__ float sm[8 * SSTRIDE];   // 36864 B

    const int lane = threadIdx.x & 63;
    const int wv   = threadIdx.x >> 6;
    const int blk  = blockIdx.x;

    // blk = ((b*16 + sy)*256 + x) : x fastest for L2 locality of shared x+1 cols
    const int b  = blk >> 12;
    const int r  = blk & 4095;
    const int sy = r >> 8;
    const int x  = r & 255;
    const int y0 = sy * RPB;
    const int xc1 = (x + 1 < X) ? (x + 1) : (X - 1);
    const bool xvalid = (x < X - 1);

    const float* ob = outs + (size_t)b * 3 * CO;
    const float* tb = tgts + (size_t)b * 4 * CO;

    const int row_l = wv * 4 + (lane >> 4);   // 0..15 (block-local y row)
    const int zi    = (lane & 15) << 2;       // 0,4,...,60
    const int y_own = y0 + row_l;
    const bool yvalid = (y_own < Y - 1);

    // ---- direct NT loads (pointwise targets), issued before staging ----
    const float* tb0 = tb + (size_t)x * YZ + (size_t)y_own * Z + zi;
    const fvec4 tbx = __builtin_nontemporal_load((const fvec4*)(tb0 + 0 * CO));
    const fvec4 tby = __builtin_nontemporal_load((const fvec4*)(tb0 + 1 * CO));
    const fvec4 tbz = __builtin_nontemporal_load((const fvec4*)(tb0 + 2 * CO));

    // ---- async global->LDS staging: 8 streams, wave wv does streams 2wv, 2wv+1 ----
    const int y16 = (y0 + 16 < Y) ? (y0 + 16) : (Y - 1);
    #pragma unroll
    for (int j = 0; j < 2; ++j) {
        const int s   = wv * 2 + j;
        const int col = s >> 2;             // 0..1
        const int ch  = s & 3;              // 0..2 = bx,by,bz ; 3 = zc
        const int xs  = col ? xc1 : x;
        const float* gbase = (ch < 3 ? ob + (size_t)ch * CO : tb + (size_t)3 * CO)
                           + (size_t)xs * YZ;
        const float* gsrc  = gbase + (size_t)y0 * Z;       // rows y0..y0+15: 4 KB contiguous
        float* ldst = sm + s * SSTRIDE;
        #pragma unroll
        for (int k = 0; k < 4; ++k) {       // 4 x (64 lanes x 16 B) = 4 KB
            __builtin_amdgcn_global_load_lds((gptr_t)(gsrc + k * 256 + lane * 4),
                                             (lptr_t)(ldst + k * 256 + lane * 4),
                                             16, 0, 0);
        }
        // row 16 (halo), source clamped to y=255 for the last segment: 256 B, width 4
        const float* gsrc16 = gbase + (size_t)y16 * Z;
        __builtin_amdgcn_global_load_lds((gptr_t)(gsrc16 + lane),
                                         (lptr_t)(ldst + 16 * 64 + lane),
                                         4, 0, 0);
    }
    __syncthreads();   // drains vmcnt: staging + NT loads complete

    // LDS tile accessor (16B-aligned float4 reads)
    #define SMF4(col, ch, row) (*(const fvec4*)(sm + ((col) * 4 + (ch)) * SSTRIDE + (row) * 64 + zi))

    const fvec4 obx   = SMF4(0, 0, row_l);
    const fvec4 oby   = SMF4(0, 1, row_l);
    const fvec4 obz   = SMF4(0, 2, row_l);
    const fvec4 tzc   = SMF4(0, 3, row_l);
    const fvec4 obx1  = SMF4(1, 0, row_l);
    const fvec4 oby1  = SMF4(1, 1, row_l);
    const fvec4 obz1  = SMF4(1, 2, row_l);
    const fvec4 tzc1  = SMF4(1, 3, row_l);
    const fvec4 obxy  = SMF4(0, 0, row_l + 1);
    const fvec4 obyy  = SMF4(0, 1, row_l + 1);
    const fvec4 obzy  = SMF4(0, 2, row_l + 1);
    const fvec4 tzcy  = SMF4(0, 3, row_l + 1);
    const fvec4 obxy1 = SMF4(1, 0, row_l + 1);
    const fvec4 obyy1 = SMF4(1, 1, row_l + 1);
    const fvec4 obzy1 = SMF4(1, 2, row_l + 1);
    const fvec4 tzcy1 = SMF4(1, 3, row_l + 1);

    double s_pt = 0.0;
    double s_dv = 0.0;

    // ---- pointwise losses ----
    {
        float pt4 = 0.0f;
        #pragma unroll
        for (int c = 0; c < 4; ++c) {
            const float bxp = F4C(obx, c), byp = F4C(oby, c), bzp = F4C(obz, c);
            const float bxt = F4C(tbx, c), byt = F4C(tby, c), bzt = F4C(tbz, c);
            const float bxt2 = bxt * bxt, byt2 = byt * byt, bzt2 = bzt * bzt;
            const float dxy = bxt2 + byt2;
            const float t1 = bxp * bxp + byp * byp - dxy;
            const float e1 = t1 * t1 * RCPF(dxy + EPSc);
            const float dd = bzp - bzt;
            const float dd2 = dd * dd;
            const float e2 = dd2 * dd2 * RCPF(bzt2 + EPSc);
            const float cr = bxp * byt - byp * bxt;
            const float e3 = cr * cr * RCPF(dxy + bzt2 + EPSc);
            pt4 += e1 + e2 + e3;
        }
        s_pt += (double)pt4;
    }

    // ---- divergence: per-z-level shared partial sums (round-4 algebra) ----
    if (xvalid) {                        // block-uniform
        float sxp[5], sxm[5], syp[5], sym[5];
        float zxp[5], zxm[5], zyp[5], zym[5];
        float Sx[5], Sy[5], Sz[5], G2[5];

        #pragma unroll
        for (int t = 0; t < 4; ++t) {
            const float bx00 = F4C(obx, t),   bx10 = F4C(obx1, t);
            const float bx01 = F4C(obxy, t),  bx11 = F4C(obxy1, t);
            const float by00 = F4C(oby, t),   by10 = F4C(oby1, t);
            const float by01 = F4C(obyy, t),  by11 = F4C(obyy1, t);
            const float bz00 = F4C(obz, t),   bz10 = F4C(obz1, t);
            const float bz01 = F4C(obzy, t),  bz11 = F4C(obzy1, t);
            const float zc00 = F4C(tzc, t),   zc10 = F4C(tzc1, t);
            const float zc01 = F4C(tzcy, t),  zc11 = F4C(tzcy1, t);

            sxp[t] = bx10 + bx11;   sxm[t] = bx00 + bx01;
            syp[t] = by01 + by11;   sym[t] = by00 + by10;
            zxp[t] = zc10 + zc11;   zxm[t] = zc00 + zc01;
            zyp[t] = zc01 + zc11;   zym[t] = zc00 + zc10;
            Sx[t] = sxp[t] + sxm[t];
            Sy[t] = syp[t] + sym[t];
            Sz[t] = (bz00 + bz01) + (bz10 + bz11);
            G2[t] = 0.025f * Sz[t]
                  + SIXTH * ((bx00 + sxp[t]) * (zc00 - zc10)
                           + (bx01 + sxp[t]) * (zc01 - zc11)
                           + (by10 + syp[t]) * (zc10 - zc11)
                           + (by00 + syp[t]) * (zc00 - zc01));
        }
        // level 4 = lane+1's level 0 (z is the lane-contiguous dim)
        sxp[4] = __shfl_down(sxp[0], 1);
        sxm[4] = __shfl_down(sxm[0], 1);
        syp[4] = __shfl_down(syp[0], 1);
        sym[4] = __shfl_down(sym[0], 1);
        zxp[4] = __shfl_down(zxp[0], 1);
        zxm[4] = __shfl_down(zxm[0], 1);
        zyp[4] = __shfl_down(zyp[0], 1);
        zym[4] = __shfl_down(zym[0], 1);
        Sz[4]  = __shfl_down(Sz[0],  1);
        G2[4]  = __shfl_down(G2[0],  1);
        Sx[4] = sxp[4] + sxm[4];
        Sy[4] = syp[4] + sym[4];

        float dv4 = 0.0f;
        #pragma unroll
        for (int c = 0; c < 4; ++c) {
            const float fx = (sxp[c] + sxp[c+1]) * (zxp[c+1] - zxp[c])
                           - (sxm[c] + sxm[c+1]) * (zxm[c+1] - zxm[c])
                           + (syp[c] + syp[c+1]) * (zyp[c+1] - zyp[c])
                           - (sym[c] + sym[c+1]) * (zym[c+1] - zym[c]);
            const float num2 = 0.125f * fx + (G2[c+1] - G2[c]);
            const float SxS = Sx[c] + Sx[c+1];
            const float SyS = Sy[c] + Sy[c+1];
            const float SzS = Sz[c] + Sz[c+1];
            const float q = SxS * SxS + SyS * SyS + SzS * SzS;
            const float den = 0.015625f * q + EPSc;
            const float v = num2 * num2 * RCPF(den);
            const bool ok = yvalid && ((zi + c) < Z - 1);
            dv4 += ok ? v : 0.0f;
        }
        s_dv += (double)dv4;
    }

    // wave reduction (64 lanes)
    for (int off = 32; off > 0; off >>= 1) {
        s_pt += __shfl_down(s_pt, off);
        s_dv += __shfl_down(s_dv, off);
    }

    __shared__ double lds_pt[WPB];
    __shared__ double lds_dv[WPB];
    if (lane == 0) { lds_pt[wv] = s_pt; lds_dv[wv] = s_dv; }
    __syncthreads();
    if (threadIdx.x == 0) {
        double p = 0.0, d = 0.0;
        #pragma unroll
        for (int w = 0; w < WPB; ++w) { p += lds_pt[w]; d += lds_dv[w]; }
        partial[2 * blockIdx.x]     = p;
        partial[2 * blockIdx.x + 1] = d;
    }
}

__global__ __launch_bounds__(256) void loss_finalize(const double* __restrict__ partial,
                                                     float* __restrict__ out) {
    double s0 = 0.0, s1 = 0.0;
    for (int i = threadIdx.x; i < BLOCKS; i += 256) {
        s0 += partial[2 * i];
        s1 += partial[2 * i + 1];
    }
    const int lane = threadIdx.x & 63;
    const int wave = threadIdx.x >> 6;
    for (int off = 32; off > 0; off >>= 1) {
        s0 += __shfl_down(s0, off);
        s1 += __shfl_down(s1, off);
    }
    __shared__ double l0[4], l1[4];
    if (lane == 0) { l0[wave] = s0; l1[wave] = s1; }
    __syncthreads();
    if (threadIdx.x == 0) {
        double p = 0.0, d = 0.0;
        #pragma unroll
        for (int w = 0; w < 4; ++w) { p += l0[w]; d += l1[w]; }
        // out0 = W_B*loss_b + W_PARALLEL*loss_parallel = 1000 * sum_pt / N
        const double out0 = 1000.0 * (p / (double)N_PTS);
        // s_dv accumulates v = num2^2/den with num = 0.1*num2:
        //   out1 = 100 * (0.01 * sum_v / M) / 1e-4 = 1e4 * sum_v / M
        const double out1 = 10000.0 * (d / (double)M_CELLS);
        out[0] = (float)out0;
        out[1] = (float)out1;
    }
}

extern "C" void kernel_launch(void* const* d_in, const int* in_sizes, int n_in,
                              void* d_out, int out_size, void* d_ws, size_t ws_size,
                              hipStream_t stream) {
    const float* outs = (const float*)d_in[0];   // (2,3,256,256,64) f32
    const float* tgts = (const float*)d_in[1];   // (2,4,256,256,64) f32
    float* out = (float*)d_out;                  // 2 scalars f32
    double* partial = (double*)d_ws;             // BLOCKS*2 doubles = 128 KB

    loss_main<<<BLOCKS, TPB, 0, stream>>>(outs, tgts, partial);
    loss_finalize<<<1, 256, 0, stream>>>(partial, out);
}